// Round 2
// baseline (18.244 us; speedup 1.0000x reference)
//
#include <hip/hip_runtime.h>

// out[b, q] = prod_{j<=q} cos(x[b, j])   (q_weights provably irrelevant:
// RZ adds diagonal phases only; CNOTs permute basis states; Z-expectations
// of the product state factorize -> Heisenberg Z_q -> Z_0..Z_q).
//
// R1: grid-stride, 4 rows/thread, loads batched before use (MLP=4/lane).

#define ROWS_PER_THREAD 4

__global__ __launch_bounds__(256) void qlayer_kernel(
    const float* __restrict__ x, float* __restrict__ out, int batch) {
    const int tid = blockIdx.x * blockDim.x + threadIdx.x;
    const int T = gridDim.x * blockDim.x;  // total threads

    float4 t[ROWS_PER_THREAD];
#pragma unroll
    for (int k = 0; k < ROWS_PER_THREAD; ++k) {
        size_t row = (size_t)tid + (size_t)k * T;
        t[k] = *reinterpret_cast<const float4*>(x + row * 16);  // cols 0..3
    }
#pragma unroll
    for (int k = 0; k < ROWS_PER_THREAD; ++k) {
        size_t row = (size_t)tid + (size_t)k * T;
        float c0 = __cosf(t[k].x);
        float c1 = c0 * __cosf(t[k].y);
        float c2 = c1 * __cosf(t[k].z);
        float c3 = c2 * __cosf(t[k].w);
        float4 o;
        o.x = c0; o.y = c1; o.z = c2; o.w = c3;
        *reinterpret_cast<float4*>(out + row * 4) = o;  // coalesced 16B/lane
    }
}

extern "C" void kernel_launch(void* const* d_in, const int* in_sizes, int n_in,
                              void* d_out, int out_size, void* d_ws, size_t ws_size,
                              hipStream_t stream) {
    const float* x = (const float*)d_in[0];
    float* out = (float*)d_out;
    int batch = in_sizes[0] / 16;                 // 1048576
    int block = 256;
    int threads = batch / ROWS_PER_THREAD;        // 262144
    int grid = threads / block;                   // 1024 blocks (4/CU)
    qlayer_kernel<<<grid, block, 0, stream>>>(x, out, batch);
}

// Round 4
// 17.854 us; speedup vs baseline: 1.0219x; 1.0219x over previous
//
#include <hip/hip_runtime.h>

// out[b, q] = prod_{j<=q} cos(x[b, j])   (q_weights provably irrelevant:
// RZ adds diagonal phases only; CNOTs permute basis states; Z-expectations
// of the product state factorize -> Heisenberg Z_q -> Z_0..Z_q).
//
// R3: R2 with compile fix — native ext_vector float4 for the
//     nontemporal builtin (HIP_vector_type not accepted).

typedef float f32x4 __attribute__((ext_vector_type(4)));

#define ROWS_PER_THREAD 2

__global__ __launch_bounds__(256) void qlayer_kernel(
    const float* __restrict__ x, float* __restrict__ out, int batch) {
    const int tid = blockIdx.x * blockDim.x + threadIdx.x;
    const int T = gridDim.x * blockDim.x;  // total threads

    f32x4 t[ROWS_PER_THREAD];
#pragma unroll
    for (int k = 0; k < ROWS_PER_THREAD; ++k) {
        size_t row = (size_t)tid + (size_t)k * T;
        t[k] = *reinterpret_cast<const f32x4*>(x + row * 16);  // cols 0..3
    }
#pragma unroll
    for (int k = 0; k < ROWS_PER_THREAD; ++k) {
        size_t row = (size_t)tid + (size_t)k * T;
        float c0 = __cosf(t[k].x);
        float c1 = c0 * __cosf(t[k].y);
        float c2 = c1 * __cosf(t[k].z);
        float c3 = c2 * __cosf(t[k].w);
        f32x4 o;
        o.x = c0; o.y = c1; o.z = c2; o.w = c3;
        // Non-temporal: don't allocate out in L2/L3 -> x stays cache-resident.
        __builtin_nontemporal_store(o, reinterpret_cast<f32x4*>(out + row * 4));
    }
}

extern "C" void kernel_launch(void* const* d_in, const int* in_sizes, int n_in,
                              void* d_out, int out_size, void* d_ws, size_t ws_size,
                              hipStream_t stream) {
    const float* x = (const float*)d_in[0];
    float* out = (float*)d_out;
    int batch = in_sizes[0] / 16;                 // 1048576
    int block = 256;
    int threads = batch / ROWS_PER_THREAD;        // 524288
    int grid = threads / block;                   // 2048 blocks (8/CU)
    qlayer_kernel<<<grid, block, 0, stream>>>(x, out, batch);
}

// Round 5
// 16.427 us; speedup vs baseline: 1.1106x; 1.0868x over previous
//
#include <hip/hip_runtime.h>

// out[b, q] = prod_{j<=q} cos(x[b, j])   (q_weights provably irrelevant:
// RZ adds diagonal phases only; CNOTs permute basis states; Z-expectations
// of the product state factorize -> Heisenberg Z_q -> Z_0..Z_q).
//
// R4: R0 structure (1 row/thread — fastest so far) + nontemporal LOADS
//     and stores: both streams are touch-once, so bypass cache alloc
//     entirely (pure streaming, like the 6.9 TB/s fill kernels).

typedef float f32x4 __attribute__((ext_vector_type(4)));

__global__ __launch_bounds__(256) void qlayer_kernel(
    const float* __restrict__ x, float* __restrict__ out, int batch) {
    int b = blockIdx.x * blockDim.x + threadIdx.x;
    if (b >= batch) return;
    f32x4 t = __builtin_nontemporal_load(
        reinterpret_cast<const f32x4*>(x + (size_t)b * 16));  // cols 0..3
    float c0 = __cosf(t.x);
    float c1 = c0 * __cosf(t.y);
    float c2 = c1 * __cosf(t.z);
    float c3 = c2 * __cosf(t.w);
    f32x4 o;
    o.x = c0; o.y = c1; o.z = c2; o.w = c3;
    __builtin_nontemporal_store(o, reinterpret_cast<f32x4*>(out + (size_t)b * 4));
}

extern "C" void kernel_launch(void* const* d_in, const int* in_sizes, int n_in,
                              void* d_out, int out_size, void* d_ws, size_t ws_size,
                              hipStream_t stream) {
    const float* x = (const float*)d_in[0];
    float* out = (float*)d_out;
    int batch = in_sizes[0] / 16;                 // 1048576
    int block = 256;
    int grid = (batch + block - 1) / block;       // 4096 blocks
    qlayer_kernel<<<grid, block, 0, stream>>>(x, out, batch);
}